// Round 1
// baseline (781.595 us; speedup 1.0000x reference)
//
#include <hip/hip_runtime.h>
#include <hip/hip_bf16.h>

// Decoder: B=64, T=32, S_ENC=64, E=H=1024, V=32000.
// Key structural wins:
//  - softmax over size-1 axis == 1.0  =>  ctx[b] = sum_s enc[b,s,:]  (attn_W unused)
//  - comb projection does not feed the recurrence => batched GEMM over all t,
//    with ctx appended on the K axis (K=3072) so ctx_proj needs no separate pass
//  - only gates = x W_ih^T + h W_hh^T is sequential; x W_ih^T precomputed.
// All matmuls in bf16 MFMA (16x16x32), f32 accumulate.

typedef unsigned short u16;
typedef short s8v __attribute__((ext_vector_type(8)));   // 8 bf16 operand (4 VGPRs)
typedef float f4v __attribute__((ext_vector_type(4)));   // 16x16 accum (4 f32)

__device__ __forceinline__ u16 f2bf(float f) {
  unsigned x = __float_as_uint(f);
  unsigned r = (x + 0x7fffu + ((x >> 16) & 1u)) >> 16;   // RNE
  return (u16)r;
}
__device__ __forceinline__ float bf2f(u16 u) {
  return __uint_as_float(((unsigned)u) << 16);
}

// ---------------------------------------------------------------------------
// Generic C = A(bf16,[M][K]) * B(f32,[N][ldb],row=K-contig)^T + bias epilogue.
// BM=BN=128, BK=64, 256 thr (4 waves, 2x2), each wave 64x64 = 4x4 frags.
// EPI: 1 = bf16 out (+bias), 2 = bf16 tanh(+bias), 3 = f32 out (+bias)
// ---------------------------------------------------------------------------
template <int EPI>
__global__ __launch_bounds__(256, 2) void gemm_bt(
    const u16* __restrict__ A, const float* __restrict__ Bm,
    const float* __restrict__ bias, void* __restrict__ Cp,
    int K, int ldb, int ldc, int gridM) {
  __shared__ __align__(16) u16 As[128][72];  // 64 data + 8 pad (144B rows)
  __shared__ __align__(16) u16 Bs[128][72];

  int nb = (int)gridDim.x;
  int bid = (int)blockIdx.x;
  // bijective XCD swizzle (m204) over m-fastest ordering -> B-panel L2 reuse
  int q8 = nb >> 3, r8 = nb & 7;
  int xcd = bid & 7, idx = bid >> 3;
  int swz = (xcd < r8 ? xcd * (q8 + 1) : r8 * (q8 + 1) + (xcd - r8) * q8) + idx;
  int mt = swz % gridM, nt = swz / gridM;
  long bm = (long)mt * 128, bn = (long)nt * 128;

  int tid = threadIdx.x;
  int w = tid >> 6, l = tid & 63;
  int wm = (w & 1) * 64, wn = (w >> 1) * 64;
  int lr = l & 15, lg = l >> 4;

  f4v acc[4][4];
#pragma unroll
  for (int i = 0; i < 4; ++i)
#pragma unroll
    for (int j = 0; j < 4; ++j) acc[i][j] = (f4v){0.f, 0.f, 0.f, 0.f};

  for (int kt = 0; kt < K; kt += 64) {
    // stage: 128 rows x 64 cols; 1024 16B-chunks, 4 per thread
#pragma unroll
    for (int p = 0; p < 4; ++p) {
      int ch = p * 256 + tid;
      int row = ch >> 3, cc = ch & 7;
      *(uint4*)((char*)(&As[0][0]) + row * 144 + cc * 16) =
          *(const uint4*)(A + (bm + row) * (long)K + kt + cc * 8);
      const float* bp = Bm + (bn + row) * (long)ldb + kt + cc * 8;
      float4 b0 = *(const float4*)bp;
      float4 b1 = *(const float4*)(bp + 4);
      union { u16 t8[8]; uint4 v; } cv;
      cv.t8[0] = f2bf(b0.x); cv.t8[1] = f2bf(b0.y);
      cv.t8[2] = f2bf(b0.z); cv.t8[3] = f2bf(b0.w);
      cv.t8[4] = f2bf(b1.x); cv.t8[5] = f2bf(b1.y);
      cv.t8[6] = f2bf(b1.z); cv.t8[7] = f2bf(b1.w);
      *(uint4*)((char*)(&Bs[0][0]) + row * 144 + cc * 16) = cv.v;
    }
    __syncthreads();
#pragma unroll
    for (int ks = 0; ks < 2; ++ks) {
      int kb = ks * 64 + lg * 16;  // byte offset: k = ks*32 + 8*lg (contig 8)
      s8v av[4], bv[4];
#pragma unroll
      for (int i = 0; i < 4; ++i) {
        av[i] = *(const s8v*)((const char*)(&As[0][0]) + (wm + i * 16 + lr) * 144 + kb);
        bv[i] = *(const s8v*)((const char*)(&Bs[0][0]) + (wn + i * 16 + lr) * 144 + kb);
      }
#pragma unroll
      for (int mi = 0; mi < 4; ++mi)
#pragma unroll
        for (int ni = 0; ni < 4; ++ni)
          acc[mi][ni] = __builtin_amdgcn_mfma_f32_16x16x32_bf16(
              av[mi], bv[ni], acc[mi][ni], 0, 0, 0);
    }
    __syncthreads();
  }
  // epilogue: C/D layout col=lane&15, row=4*(lane>>4)+reg (m89/m91 verified)
#pragma unroll
  for (int mi = 0; mi < 4; ++mi) {
#pragma unroll
    for (int q = 0; q < 4; ++q) {
      long row = bm + wm + mi * 16 + lg * 4 + q;
#pragma unroll
      for (int ni = 0; ni < 4; ++ni) {
        long col = bn + wn + ni * 16 + lr;
        float v = acc[mi][ni][q] + bias[col];
        if (EPI == 2) v = tanhf(v);
        if (EPI == 3)
          ((float*)Cp)[row * (long)ldc + col] = v;
        else
          ((u16*)Cp)[row * (long)ldc + col] = f2bf(v);
      }
    }
  }
}

// ---------------------------------------------------------------------------
// One LSTM step. 64 blocks (hidden slice of 16 each) x 512 thr (8 waves).
// Wave w: gate g=w>>1, batch-half mh=w&1. gates = h_prev Whh^T (+xproj incl
// x W_ih^T + bias). Cross-gate exchange via LDS; updates c,h slice.
// h double-buffered across launches (no intra-kernel grid sync needed).
// ---------------------------------------------------------------------------
__global__ __launch_bounds__(512, 1) void lstm_step(
    const u16* __restrict__ Whh, const u16* __restrict__ xproj,
    const u16* __restrict__ h_in, u16* __restrict__ h_next,
    float* __restrict__ c_buf, u16* __restrict__ a2,
    float* __restrict__ hf, float* __restrict__ cf, int t) {
  __shared__ __align__(16) u16 Ah[64][136];  // h tile [64b][128k] (+pad)
  __shared__ __align__(16) u16 Bw[64][136];  // Whh rows [4g*16][128k]
  __shared__ float Gs[4][64][16];            // gate preacts [g][b][r]

  int j = blockIdx.x;
  int tid = threadIdx.x;
  int w = tid >> 6, l = tid & 63;
  int g = w >> 1, mh = w & 1;
  int lr = l & 15, lg = l >> 4;

  f4v acc[2] = {{0.f, 0.f, 0.f, 0.f}, {0.f, 0.f, 0.f, 0.f}};

  for (int kc = 0; kc < 8; ++kc) {
    int kk = kc * 128;
#pragma unroll
    for (int p = 0; p < 2; ++p) {
      int ch = p * 512 + tid;        // 1024 chunks of 16B
      int row = ch >> 4, cc = ch & 15;
      *(uint4*)((char*)(&Ah[0][0]) + row * 272 + cc * 16) =
          *(const uint4*)(h_in + row * 1024 + kk + cc * 8);
      const u16* src = Whh +
          ((long)((row >> 4) * 1024 + (j << 4) + (row & 15))) * 1024 + kk + cc * 8;
      *(uint4*)((char*)(&Bw[0][0]) + row * 272 + cc * 16) = *(const uint4*)src;
    }
    __syncthreads();
#pragma unroll
    for (int ks = 0; ks < 4; ++ks) {
      int kb = ks * 64 + lg * 16;
      s8v bv = *(const s8v*)((const char*)(&Bw[0][0]) + (g * 16 + lr) * 272 + kb);
#pragma unroll
      for (int mi = 0; mi < 2; ++mi) {
        int row = (mh * 2 + mi) * 16 + lr;
        s8v av = *(const s8v*)((const char*)(&Ah[0][0]) + row * 272 + kb);
        acc[mi] = __builtin_amdgcn_mfma_f32_16x16x32_bf16(av, bv, acc[mi], 0, 0, 0);
      }
    }
    __syncthreads();
  }

#pragma unroll
  for (int mi = 0; mi < 2; ++mi) {
#pragma unroll
    for (int q = 0; q < 4; ++q) {
      int b = (mh * 2 + mi) * 16 + lg * 4 + q;
      float pre = acc[mi][q] +
          bf2f(xproj[(long)(b * 32 + t) * 4096 + g * 1024 + (j << 4) + lr]);
      Gs[g][b][lr] = pre;
    }
  }
  __syncthreads();

#pragma unroll
  for (int e = 0; e < 2; ++e) {
    int p = tid * 2 + e;
    int b = p >> 4, r = p & 15;
    int col = (j << 4) + r;
    float iv = Gs[0][b][r], fv = Gs[1][b][r], gv = Gs[2][b][r], ov = Gs[3][b][r];
    iv = 1.f / (1.f + expf(-iv));
    fv = 1.f / (1.f + expf(-fv));
    ov = 1.f / (1.f + expf(-ov));
    gv = tanhf(gv);
    float co = c_buf[b * 1024 + col];
    float cn = fv * co + iv * gv;
    float hn = ov * tanhf(cn);
    c_buf[b * 1024 + col] = cn;
    h_next[b * 1024 + col] = f2bf(hn);
    a2[(long)(b * 32 + t) * 3072 + col] = f2bf(hn);
    if (t == 31) {
      hf[b * 1024 + col] = hn;
      cf[b * 1024 + col] = cn;
    }
  }
}

// ---------------------------- prep kernels ---------------------------------
__global__ void k_misc(const float* __restrict__ bih, const float* __restrict__ bhh,
                       const float* __restrict__ h0, const float* __restrict__ c0,
                       float* __restrict__ bias, u16* __restrict__ hbuf0,
                       float* __restrict__ cbuf) {
  int i = blockIdx.x * 256 + threadIdx.x;
  if (i < 4096) bias[i] = bih[i] + bhh[i];
  if (i < 65536) {
    hbuf0[i] = f2bf(h0[i]);
    cbuf[i] = c0[i];
  }
}

__global__ void k_cvt(const float* __restrict__ src, u16* __restrict__ dst, int n) {
  int i = blockIdx.x * blockDim.x + threadIdx.x;
  int stride = gridDim.x * blockDim.x;
  for (; i < n; i += stride) dst[i] = f2bf(src[i]);
}

__global__ void k_emb(const int* __restrict__ inp, const float* __restrict__ emb,
                      u16* __restrict__ embx) {
  long i = (long)blockIdx.x * 256 + threadIdx.x;  // 2048*1024 total
  int r = (int)(i >> 10), k = (int)(i & 1023);
  embx[i] = f2bf(emb[(long)inp[r] * 1024 + k]);
}

// ctx[b,d] = sum_s enc[b,s,d]; broadcast as bf16 into A2 cols 1024..3071 for all t
__global__ void k_ctx(const float* __restrict__ enc, u16* __restrict__ a2) {
  int b = blockIdx.x;
  int tid = threadIdx.x;
  for (int d = tid; d < 2048; d += 256) {
    float s = 0.f;
    for (int si = 0; si < 64; ++si) s += enc[((long)(b * 64 + si)) * 2048 + d];
    u16 v = f2bf(s);
    for (int t = 0; t < 32; ++t) a2[(long)(b * 32 + t) * 3072 + 1024 + d] = v;
  }
}

// ---------------------------------------------------------------------------
extern "C" void kernel_launch(void* const* d_in, const int* in_sizes, int n_in,
                              void* d_out, int out_size, void* d_ws, size_t ws_size,
                              hipStream_t stream) {
  (void)in_sizes; (void)n_in; (void)out_size; (void)ws_size;
  const int*   inputs = (const int*)d_in[0];
  const float* enc    = (const float*)d_in[1];
  const float* h0     = (const float*)d_in[2];
  const float* c0     = (const float*)d_in[3];
  const float* emb    = (const float*)d_in[4];
  const float* Wih    = (const float*)d_in[5];
  const float* Whh    = (const float*)d_in[6];
  const float* bih    = (const float*)d_in[7];
  const float* bhh    = (const float*)d_in[8];
  // d_in[9] = attn_W: mathematically unused (softmax over size-1 axis == 1)
  const float* combW  = (const float*)d_in[10];
  const float* combb  = (const float*)d_in[11];
  const float* outW   = (const float*)d_in[12];
  const float* outb   = (const float*)d_in[13];
  float* out = (float*)d_out;

  char* ws = (char*)d_ws;
  size_t off = 0;
  auto alloc = [&](size_t bytes) {
    char* p = ws + off;
    off += (bytes + 255) & ~(size_t)255;
    return p;
  };
  u16*   WHH_BF = (u16*)  alloc(4096ull * 1024 * 2);   // bf16 W_hh
  u16*   XPROJ  = (u16*)  alloc(2048ull * 4096 * 2);   // x W_ih^T + bias (bf16)
  u16*   EMBX   = (u16*)  alloc(2048ull * 1024 * 2);   // gathered emb (bf16)
  u16*   A2     = (u16*)  alloc(2048ull * 3072 * 2);   // [h_seq | ctx] (bf16)
  u16*   OUTS   = (u16*)  alloc(2048ull * 1024 * 2);   // tanh comb outputs (bf16)
  float* BIAS   = (float*)alloc(4096 * 4);             // b_ih + b_hh
  u16*   HBUF   = (u16*)  alloc(2ull * 65536 * 2);     // h double buffer (bf16)
  float* CBUF   = (float*)alloc(65536 * 4);            // c state (f32)
  // total ws use ~46.7 MB

  k_misc<<<dim3(256), dim3(256), 0, stream>>>(bih, bhh, h0, c0, BIAS, HBUF, CBUF);
  k_cvt<<<dim3(2048), dim3(256), 0, stream>>>(Whh, WHH_BF, 4096 * 1024);
  k_emb<<<dim3(8192), dim3(256), 0, stream>>>(inputs, emb, EMBX);
  k_ctx<<<dim3(64), dim3(256), 0, stream>>>(enc, A2);

  // GEMM1: XPROJ[2048][4096] = EMBX @ W_ih^T + (b_ih+b_hh)
  gemm_bt<1><<<dim3(512), dim3(256), 0, stream>>>(EMBX, Wih, BIAS, XPROJ,
                                                  1024, 1024, 4096, 16);
  // 32 sequential LSTM steps
  for (int t = 0; t < 32; ++t) {
    u16* hin  = HBUF + (t & 1) * 65536;
    u16* hout = HBUF + ((t + 1) & 1) * 65536;
    lstm_step<<<dim3(64), dim3(512), 0, stream>>>(
        WHH_BF, XPROJ, hin, hout, CBUF, A2,
        out + 65536000, out + 65536000 + 65536, t);
  }
  // GEMM2: OUTS = tanh([h_seq|ctx] @ comb_W^T + comb_b)   (K=3072)
  gemm_bt<2><<<dim3(128), dim3(256), 0, stream>>>(A2, combW, combb, OUTS,
                                                  3072, 3072, 1024, 16);
  // GEMM3: logits = OUTS @ out_W^T + out_b  -> d_out[0:65,536,000]
  gemm_bt<3><<<dim3(4000), dim3(256), 0, stream>>>(OUTS, outW, outb, d_out,
                                                   1024, 1024, 32000, 16);
}

// Round 2
// 695.203 us; speedup vs baseline: 1.1243x; 1.1243x over previous
//
#include <hip/hip_runtime.h>
#include <hip/hip_bf16.h>

// Decoder: B=64, T=32, S_ENC=64, E=H=1024, V=32000.
//  - softmax over size-1 axis == 1.0 => ctx[b] = sum_s enc[b,s,:] (attn_W unused)
//  - comb projection batched over all t with ctx appended on K axis (K=3072)
//  - only gates = x W_ih^T + h W_hh^T is sequential; x W_ih^T precomputed.
// Round 2: global_load_lds (m97-structure) GEMMs on pre-converted bf16 weights;
// LSTM step re-parallelized to 128 blocks x 512 thr with async staging.

typedef unsigned short u16;
typedef unsigned int u32;
typedef short s8v __attribute__((ext_vector_type(8)));   // 8 bf16 (4 VGPRs)
typedef float f4v __attribute__((ext_vector_type(4)));   // 16x16 accum

__device__ __forceinline__ u16 f2bf(float f) {
  unsigned x = __float_as_uint(f);
  return (u16)((x + 0x7fffu + ((x >> 16) & 1u)) >> 16);   // RNE
}
__device__ __forceinline__ float bf2f(u16 u) {
  return __uint_as_float(((unsigned)u) << 16);
}

// async 16B global->LDS; lds base must be wave-uniform (HW adds lane*16)
__device__ __forceinline__ void gl_lds16(const void* g, void* l) {
  __builtin_amdgcn_global_load_lds(
      (const __attribute__((address_space(1))) u32*)g,
      (__attribute__((address_space(3))) u32*)l, 16, 0, 0);
}

__device__ __forceinline__ int xcd_swz(int bid, int nb) {
  int q8 = nb >> 3, r8 = nb & 7;
  int xcd = bid & 7, idx = bid >> 3;
  return (xcd < r8 ? xcd * (q8 + 1) : r8 * (q8 + 1) + (xcd - r8) * q8) + idx;
}

// ---------------------------------------------------------------------------
// m97-structure GEMM: C = A(bf16,[M][K]) * B(bf16,[N][K])^T + bias epilogue.
// BM=BN=128, BK=64, 256 thr (4 waves 2x2), wave = 64x64 = 4x4 frags.
// global_load_lds width-16 staging into linear LDS (no pad; 2-phase barriers).
// EPI: 1 = bf16 out, 2 = bf16 tanh, 3 = f32 out
// ---------------------------------------------------------------------------
template <int EPI>
__global__ __launch_bounds__(256, 2) void gemm_bt2(
    const u16* __restrict__ A, const u16* __restrict__ Bm,
    const float* __restrict__ bias, void* __restrict__ Cp,
    int K, int ldc, int gridM) {
  __shared__ __align__(16) u16 As[128 * 64];
  __shared__ __align__(16) u16 Bs[128 * 64];

  int swz = xcd_swz((int)blockIdx.x, (int)gridDim.x);
  int mt = swz % gridM, nt = swz / gridM;   // m-fastest: B-panel L2 reuse
  long bm = (long)mt * 128, bn = (long)nt * 128;

  int tid = threadIdx.x;
  int w = tid >> 6, l = tid & 63;
  int wm = (w & 1) * 64, wn = (w >> 1) * 64;
  int lr = l & 15, lg = l >> 4;

  f4v acc[4][4];
#pragma unroll
  for (int i = 0; i < 4; ++i)
#pragma unroll
    for (int j = 0; j < 4; ++j) acc[i][j] = (f4v){0.f, 0.f, 0.f, 0.f};

  for (int kt = 0; kt < K; kt += 64) {
#pragma unroll
    for (int p = 0; p < 4; ++p) {
      int cb = (p * 4 + w) * 64;          // wave-uniform chunk base
      int c = cb + l;                      // this lane's chunk (16B)
      int row = c >> 3, ce = (c & 7) * 8;  // 8 chunks per 128B row
      gl_lds16(A + (bm + row) * (long)K + kt + ce, &As[cb * 8]);
      gl_lds16(Bm + (bn + row) * (long)K + kt + ce, &Bs[cb * 8]);
    }
    __syncthreads();   // drains vmcnt -> staged data visible
#pragma unroll
    for (int ks = 0; ks < 2; ++ks) {
      int kb = ks * 64 + lg * 16;
      s8v av[4], bv[4];
#pragma unroll
      for (int i = 0; i < 4; ++i) {
        av[i] = *(const s8v*)((const char*)&As[0] + (wm + i * 16 + lr) * 128 + kb);
        bv[i] = *(const s8v*)((const char*)&Bs[0] + (wn + i * 16 + lr) * 128 + kb);
      }
#pragma unroll
      for (int mi = 0; mi < 4; ++mi)
#pragma unroll
        for (int ni = 0; ni < 4; ++ni)
          acc[mi][ni] = __builtin_amdgcn_mfma_f32_16x16x32_bf16(
              av[mi], bv[ni], acc[mi][ni], 0, 0, 0);
    }
    __syncthreads();
  }
#pragma unroll
  for (int mi = 0; mi < 4; ++mi) {
#pragma unroll
    for (int q = 0; q < 4; ++q) {
      long row = bm + wm + mi * 16 + lg * 4 + q;
#pragma unroll
      for (int ni = 0; ni < 4; ++ni) {
        long col = bn + wn + ni * 16 + lr;
        float v = acc[mi][ni][q] + bias[col];
        if (EPI == 2) v = tanhf(v);
        if (EPI == 3)
          ((float*)Cp)[row * (long)ldc + col] = v;
        else
          ((u16*)Cp)[row * (long)ldc + col] = f2bf(v);
      }
    }
  }
}

// ---------------------------------------------------------------------------
// Fallback GEMM with f32 B (in-kernel convert) for when ws can't hold bf16 B.
// ---------------------------------------------------------------------------
template <int EPI>
__global__ __launch_bounds__(256, 2) void gemm_btf(
    const u16* __restrict__ A, const float* __restrict__ Bm,
    const float* __restrict__ bias, void* __restrict__ Cp,
    int K, int ldc, int gridM) {
  __shared__ __align__(16) u16 As[128][72];
  __shared__ __align__(16) u16 Bs[128][72];
  int swz = xcd_swz((int)blockIdx.x, (int)gridDim.x);
  int mt = swz % gridM, nt = swz / gridM;
  long bm = (long)mt * 128, bn = (long)nt * 128;
  int tid = threadIdx.x;
  int w = tid >> 6, l = tid & 63;
  int wm = (w & 1) * 64, wn = (w >> 1) * 64;
  int lr = l & 15, lg = l >> 4;
  f4v acc[4][4];
#pragma unroll
  for (int i = 0; i < 4; ++i)
#pragma unroll
    for (int j = 0; j < 4; ++j) acc[i][j] = (f4v){0.f, 0.f, 0.f, 0.f};
  for (int kt = 0; kt < K; kt += 64) {
#pragma unroll
    for (int p = 0; p < 4; ++p) {
      int ch = p * 256 + tid;
      int row = ch >> 3, cc = ch & 7;
      *(uint4*)((char*)(&As[0][0]) + row * 144 + cc * 16) =
          *(const uint4*)(A + (bm + row) * (long)K + kt + cc * 8);
      const float* bp = Bm + (bn + row) * (long)K + kt + cc * 8;
      float4 b0 = *(const float4*)bp;
      float4 b1 = *(const float4*)(bp + 4);
      union { u16 t8[8]; uint4 v; } cv;
      cv.t8[0] = f2bf(b0.x); cv.t8[1] = f2bf(b0.y);
      cv.t8[2] = f2bf(b0.z); cv.t8[3] = f2bf(b0.w);
      cv.t8[4] = f2bf(b1.x); cv.t8[5] = f2bf(b1.y);
      cv.t8[6] = f2bf(b1.z); cv.t8[7] = f2bf(b1.w);
      *(uint4*)((char*)(&Bs[0][0]) + row * 144 + cc * 16) = cv.v;
    }
    __syncthreads();
#pragma unroll
    for (int ks = 0; ks < 2; ++ks) {
      int kb = ks * 64 + lg * 16;
      s8v av[4], bv[4];
#pragma unroll
      for (int i = 0; i < 4; ++i) {
        av[i] = *(const s8v*)((const char*)(&As[0][0]) + (wm + i * 16 + lr) * 144 + kb);
        bv[i] = *(const s8v*)((const char*)(&Bs[0][0]) + (wn + i * 16 + lr) * 144 + kb);
      }
#pragma unroll
      for (int mi = 0; mi < 4; ++mi)
#pragma unroll
        for (int ni = 0; ni < 4; ++ni)
          acc[mi][ni] = __builtin_amdgcn_mfma_f32_16x16x32_bf16(
              av[mi], bv[ni], acc[mi][ni], 0, 0, 0);
    }
    __syncthreads();
  }
#pragma unroll
  for (int mi = 0; mi < 4; ++mi) {
#pragma unroll
    for (int q = 0; q < 4; ++q) {
      long row = bm + wm + mi * 16 + lg * 4 + q;
#pragma unroll
      for (int ni = 0; ni < 4; ++ni) {
        long col = bn + wn + ni * 16 + lr;
        float v = acc[mi][ni][q] + bias[col];
        if (EPI == 2) v = tanhf(v);
        if (EPI == 3)
          ((float*)Cp)[row * (long)ldc + col] = v;
        else
          ((u16*)Cp)[row * (long)ldc + col] = f2bf(v);
      }
    }
  }
}

// ---------------------------------------------------------------------------
// One LSTM step. 128 blocks x 512 thr (8 waves). Block j owns h-cols
// [j*8, j*8+8) => 32 gate-rows (4 gates x 8). Wave (bq=w&3, nh=w>>2):
// batch rows bq*16..+16, gate-row half nh*16..+16; full K=1024, 32 MFMA.
// Chunked K (KC=128), double-buffered global_load_lds staging, issue-next-
// before-compute (T3-minimum). LDS reads XOR slot-swizzled (source-side
// pre-swizzle, rule #21) to kill the stride-256B 16-way bank conflict.
// ---------------------------------------------------------------------------
__global__ __launch_bounds__(512, 1) void lstm_step2(
    const u16* __restrict__ Whh, const u16* __restrict__ xproj,
    const u16* __restrict__ h_in, u16* __restrict__ h_next,
    float* __restrict__ c_buf, u16* __restrict__ a2,
    float* __restrict__ hf, float* __restrict__ cf, int t) {
  __shared__ __align__(16) u16 Hs[2][64 * 128];   // 16 KB x2
  __shared__ __align__(16) u16 Ws[2][32 * 128];   // 8 KB x2
  __shared__ float Gs[64][32];                    // 8 KB

  int j = blockIdx.x;
  int colbase = j * 8;
  int tid = threadIdx.x, w = tid >> 6, l = tid & 63;
  int bq = w & 3, nh = w >> 2;
  int lr = l & 15, lg = l >> 4;

  // stage chunk kc (K cols kc*128..+128) into buffer buf
  auto stage = [&](int buf, int kc) {
    int kk = kc * 128;
    // Hs: 64 rows x 128 cols = 1024 16B-chunks, 2 rounds of 512
#pragma unroll
    for (int rnd = 0; rnd < 2; ++rnd) {
      int cb = rnd * 512 + w * 64;       // wave-uniform
      int c = cb + l;
      int row = c >> 4, sp = c & 15;     // 16 chunks per 256B row
      int sl = sp ^ (row & 7);           // logical slot for this physical slot
      gl_lds16(h_in + row * 1024 + kk + sl * 8, &Hs[buf][cb * 8]);
    }
    // Ws: 32 rows x 128 = 512 chunks, 1 round
    {
      int cb = w * 64;
      int c = cb + l;
      int q = c >> 4, sp = c & 15;
      int sl = sp ^ (q & 7);
      int g = q >> 3, r = q & 7;
      gl_lds16(Whh + (long)(g * 1024 + colbase + r) * 1024 + kk + sl * 8,
               &Ws[buf][cb * 8]);
    }
  };

  f4v acc = {0.f, 0.f, 0.f, 0.f};
  stage(0, 0);
  __syncthreads();
  for (int kc = 0; kc < 8; ++kc) {
    int cur = kc & 1;
    if (kc < 7) stage(cur ^ 1, kc + 1);   // issue next-chunk loads first
#pragma unroll
    for (int ks = 0; ks < 4; ++ks) {
      int slot = ks * 4 + lg;             // 16B slot within row
      int ar = bq * 16 + lr, br = nh * 16 + lr;
      s8v av = *(const s8v*)((const char*)&Hs[cur][0] +
                             ar * 256 + (slot ^ (ar & 7)) * 16);
      s8v bv = *(const s8v*)((const char*)&Ws[cur][0] +
                             br * 256 + (slot ^ (br & 7)) * 16);
      acc = __builtin_amdgcn_mfma_f32_16x16x32_bf16(av, bv, acc, 0, 0, 0);
    }
    __syncthreads();   // drains vmcnt -> next buffer complete
  }

  // exchange gate partials: acc[q] -> batch b = bq*16+lg*4+q, gate-row nh*16+lr
#pragma unroll
  for (int q = 0; q < 4; ++q) Gs[bq * 16 + lg * 4 + q][nh * 16 + lr] = acc[q];
  __syncthreads();

  // elementwise update: 512 threads = 64 batch x 8 cols
  int b = tid >> 3, r = tid & 7;
  int col = colbase + r;
  float pi = Gs[b][r]      + bf2f(xproj[(long)(b * 32 + t) * 4096 + col]);
  float pf = Gs[b][8 + r]  + bf2f(xproj[(long)(b * 32 + t) * 4096 + 1024 + col]);
  float pg = Gs[b][16 + r] + bf2f(xproj[(long)(b * 32 + t) * 4096 + 2048 + col]);
  float po = Gs[b][24 + r] + bf2f(xproj[(long)(b * 32 + t) * 4096 + 3072 + col]);
  float iv = 1.f / (1.f + expf(-pi));
  float fv = 1.f / (1.f + expf(-pf));
  float ov = 1.f / (1.f + expf(-po));
  float gv = tanhf(pg);
  float co = c_buf[b * 1024 + col];
  float cn = fv * co + iv * gv;
  float hn = ov * tanhf(cn);
  c_buf[b * 1024 + col] = cn;
  h_next[b * 1024 + col] = f2bf(hn);
  a2[(long)(b * 32 + t) * 3072 + col] = f2bf(hn);
  if (t == 31) {
    hf[b * 1024 + col] = hn;
    cf[b * 1024 + col] = cn;
  }
}

// ---------------------------- prep kernels ---------------------------------
__global__ void k_misc(const float* __restrict__ bih, const float* __restrict__ bhh,
                       const float* __restrict__ h0, const float* __restrict__ c0,
                       float* __restrict__ bias, u16* __restrict__ hbuf0,
                       float* __restrict__ cbuf) {
  int i = blockIdx.x * 256 + threadIdx.x;
  if (i < 4096) bias[i] = bih[i] + bhh[i];
  if (i < 65536) {
    hbuf0[i] = f2bf(h0[i]);
    cbuf[i] = c0[i];
  }
}

__global__ void k_cvt8(const float* __restrict__ src, u16* __restrict__ dst, int n8) {
  int i = blockIdx.x * 256 + threadIdx.x;
  if (i >= n8) return;
  const float4* s = (const float4*)(src + (long)i * 8);
  float4 a = s[0], b = s[1];
  union { u16 t[8]; uint4 v; } cv;
  cv.t[0] = f2bf(a.x); cv.t[1] = f2bf(a.y); cv.t[2] = f2bf(a.z); cv.t[3] = f2bf(a.w);
  cv.t[4] = f2bf(b.x); cv.t[5] = f2bf(b.y); cv.t[6] = f2bf(b.z); cv.t[7] = f2bf(b.w);
  ((uint4*)dst)[i] = cv.v;
}

__global__ void k_emb8(const int* __restrict__ inp, const float* __restrict__ emb,
                       u16* __restrict__ dst) {
  int i = blockIdx.x * 256 + threadIdx.x;   // 262144 groups of 8
  int r = i >> 7, k8 = (i & 127) * 8;
  const float* s = emb + (long)inp[r] * 1024 + k8;
  float4 a = *(const float4*)s, b = *(const float4*)(s + 4);
  union { u16 t[8]; uint4 v; } cv;
  cv.t[0] = f2bf(a.x); cv.t[1] = f2bf(a.y); cv.t[2] = f2bf(a.z); cv.t[3] = f2bf(a.w);
  cv.t[4] = f2bf(b.x); cv.t[5] = f2bf(b.y); cv.t[6] = f2bf(b.z); cv.t[7] = f2bf(b.w);
  ((uint4*)dst)[i] = cv.v;
}

// ctx[b,d] = sum_s enc[b,s,d]; broadcast bf16 into A2 cols 1024..3071 for all t
__global__ void k_ctx2(const float* __restrict__ enc, u16* __restrict__ a2) {
  int b = blockIdx.x;
  int dg = threadIdx.x;   // 256 threads: 8-elem group each
  float s[8] = {0.f, 0.f, 0.f, 0.f, 0.f, 0.f, 0.f, 0.f};
  for (int si = 0; si < 64; ++si) {
    const float* p = enc + ((long)(b * 64 + si)) * 2048 + dg * 8;
    float4 x = *(const float4*)p, y = *(const float4*)(p + 4);
    s[0] += x.x; s[1] += x.y; s[2] += x.z; s[3] += x.w;
    s[4] += y.x; s[5] += y.y; s[6] += y.z; s[7] += y.w;
  }
  union { u16 t[8]; uint4 v; } cv;
#pragma unroll
  for (int e = 0; e < 8; ++e) cv.t[e] = f2bf(s[e]);
  for (int t = 0; t < 32; ++t)
    *(uint4*)(a2 + (long)(b * 32 + t) * 3072 + 1024 + dg * 8) = cv.v;
}

// ---------------------------------------------------------------------------
extern "C" void kernel_launch(void* const* d_in, const int* in_sizes, int n_in,
                              void* d_out, int out_size, void* d_ws, size_t ws_size,
                              hipStream_t stream) {
  (void)in_sizes; (void)n_in; (void)out_size;
  const int*   inputs = (const int*)d_in[0];
  const float* enc    = (const float*)d_in[1];
  const float* h0     = (const float*)d_in[2];
  const float* c0     = (const float*)d_in[3];
  const float* emb    = (const float*)d_in[4];
  const float* Wih    = (const float*)d_in[5];
  const float* Whh    = (const float*)d_in[6];
  const float* bih    = (const float*)d_in[7];
  const float* bhh    = (const float*)d_in[8];
  // d_in[9] = attn_W: unused (softmax over size-1 axis == all ones)
  const float* combW  = (const float*)d_in[10];
  const float* combb  = (const float*)d_in[11];
  const float* outW   = (const float*)d_in[12];
  const float* outb   = (const float*)d_in[13];
  float* out = (float*)d_out;

  char* ws = (char*)d_ws;
  size_t off = 0;
  auto alloc = [&](size_t bytes) {
    char* p = ws + off;
    off += (bytes + 255) & ~(size_t)255;
    return p;
  };
  u16*   WHH_BF = (u16*)  alloc(4096ull * 1024 * 2);
  u16*   XPROJ  = (u16*)  alloc(2048ull * 4096 * 2);
  u16*   EMBX   = (u16*)  alloc(2048ull * 1024 * 2);
  u16*   A2     = (u16*)  alloc(2048ull * 3072 * 2);
  u16*   OUTS   = (u16*)  alloc(2048ull * 1024 * 2);
  float* BIAS   = (float*)alloc(4096 * 4);
  u16*   HBUF   = (u16*)  alloc(2ull * 65536 * 2);
  float* CBUF   = (float*)alloc(65536 * 4);
  size_t off_base = off;                               // ~46.7 MB
  u16*   WIH_BF   = (u16*)alloc(4096ull * 1024 * 2);
  u16*   COMBW_BF = (u16*)alloc(1024ull * 3072 * 2);
  size_t off_w1 = off;                                 // ~61.3 MB
  u16*   OUTW_BF  = (u16*)alloc(32000ull * 1024 * 2);
  size_t off_w2 = off;                                 // ~126.9 MB
  (void)off_base;
  bool haveW1 = ws_size >= off_w1;
  bool haveW2 = ws_size >= off_w2;

  k_misc<<<dim3(256), dim3(256), 0, stream>>>(bih, bhh, h0, c0, BIAS, HBUF, CBUF);
  k_cvt8<<<dim3(2048), dim3(256), 0, stream>>>(Whh, WHH_BF, 524288);
  k_emb8<<<dim3(1024), dim3(256), 0, stream>>>(inputs, emb, EMBX);
  k_ctx2<<<dim3(64), dim3(256), 0, stream>>>(enc, A2);
  if (haveW1) {
    k_cvt8<<<dim3(2048), dim3(256), 0, stream>>>(Wih, WIH_BF, 524288);
    k_cvt8<<<dim3(1536), dim3(256), 0, stream>>>(combW, COMBW_BF, 393216);
  }
  if (haveW2)
    k_cvt8<<<dim3(16000), dim3(256), 0, stream>>>(outW, OUTW_BF, 4096000);

  // GEMM1: XPROJ[2048][4096] = EMBX @ W_ih^T + (b_ih+b_hh)
  if (haveW1)
    gemm_bt2<1><<<dim3(512), dim3(256), 0, stream>>>(EMBX, WIH_BF, BIAS, XPROJ,
                                                     1024, 4096, 16);
  else
    gemm_btf<1><<<dim3(512), dim3(256), 0, stream>>>(EMBX, Wih, BIAS, XPROJ,
                                                     1024, 4096, 16);
  // 32 sequential LSTM steps
  for (int t = 0; t < 32; ++t) {
    u16* hin  = HBUF + (t & 1) * 65536;
    u16* hout = HBUF + ((t + 1) & 1) * 65536;
    lstm_step2<<<dim3(128), dim3(512), 0, stream>>>(
        WHH_BF, XPROJ, hin, hout, CBUF, A2,
        out + 65536000, out + 65536000 + 65536, t);
  }
  // GEMM2: OUTS = tanh([h_seq|ctx] @ comb_W^T + comb_b)  (K=3072)
  if (haveW1)
    gemm_bt2<2><<<dim3(128), dim3(256), 0, stream>>>(A2, COMBW_BF, combb, OUTS,
                                                     3072, 1024, 16);
  else
    gemm_btf<2><<<dim3(128), dim3(256), 0, stream>>>(A2, combW, combb, OUTS,
                                                     3072, 1024, 16);
  // GEMM3: logits = OUTS @ out_W^T + out_b
  if (haveW2)
    gemm_bt2<3><<<dim3(4000), dim3(256), 0, stream>>>(OUTS, OUTW_BF, outb, d_out,
                                                      1024, 32000, 16);
  else
    gemm_btf<3><<<dim3(4000), dim3(256), 0, stream>>>(OUTS, outW, outb, d_out,
                                                      1024, 32000, 16);
}